// Round 1
// baseline (1462.259 us; speedup 1.0000x reference)
//
#include <hip/hip_runtime.h>
#include <hip/hip_bf16.h>
#include <stdint.h>

typedef __attribute__((ext_vector_type(8))) short short8;
typedef __attribute__((ext_vector_type(4))) float floatx4;
typedef unsigned short u16;

#define T_SEQ 1024
#define B_SZ  4
#define V_SZ  32000
#define E_SZ  1024
#define H_SZ  2048
#define M_SZ  4096      // T*B rows
#define KE    3072      // K*E
#define KCTX  3

static __device__ __forceinline__ u16 f2b(float x) {
  // fp32 -> bf16 round-to-nearest-even
  union { float f; uint32_t u; } v; v.f = x;
  uint32_t r = v.u + 0x7FFFu + ((v.u >> 16) & 1u);
  return (u16)(r >> 16);
}

// ---------------- prep 1: token gather -> X bf16 (4096 x 3072) ----------------
__global__ __launch_bounds__(256) void build_x(const int* __restrict__ tok,
                                               const float* __restrict__ emb,
                                               u16* __restrict__ X) {
  int idx = blockIdx.x * 256 + threadIdx.x;   // one thread per 8 elements
  int e0 = idx * 8;
  int row = e0 / KE;
  int col = e0 - row * KE;
  int j = col >> 10;                          // which of the K context slots
  int t = row >> 2, b = row & 3;              // row = t*B + b
  int tt = t + j - KCTX;                      // token index (zero-pad for t<K)
  int tk = (tt >= 0) ? tok[(tt << 2) + b] : 0;
  const float* s = emb + (size_t)tk * E_SZ + (col & 1023);
  floatx4 f0 = *(const floatx4*)(s);
  floatx4 f1 = *(const floatx4*)(s + 4);
  short8 o;
  o[0] = (short)f2b(f0[0]); o[1] = (short)f2b(f0[1]);
  o[2] = (short)f2b(f0[2]); o[3] = (short)f2b(f0[3]);
  o[4] = (short)f2b(f1[0]); o[5] = (short)f2b(f1[1]);
  o[6] = (short)f2b(f1[2]); o[7] = (short)f2b(f1[3]);
  *(short8*)(X + e0) = o;
}

// ---------------- prep 2: transpose fp32 (R x C) -> bf16 (C x R) ----------------
__global__ __launch_bounds__(256) void transpose_f32_bf16(const float* __restrict__ in,
                                                          u16* __restrict__ out,
                                                          int R, int C) {
  __shared__ u16 tile[32][33];
  int tx = threadIdx.x, ty = threadIdx.y;
  int x = blockIdx.x * 32 + tx;
  int ybase = blockIdx.y * 32;
  #pragma unroll
  for (int i = 0; i < 32; i += 8)
    tile[ty + i][tx] = f2b(in[(size_t)(ybase + ty + i) * C + x]);
  __syncthreads();
  int xo = ybase + tx;
  int yob = blockIdx.x * 32;
  #pragma unroll
  for (int i = 0; i < 32; i += 8)
    out[(size_t)(yob + ty + i) * R + xo] = tile[tx][ty + i];
}

// ---------------- MFMA GEMM: C[M,N] = A[M,K] * B[N,K]^T (both bf16, [rows][K]) ----
// 128x128 tile, BK=64, 256 threads = 4 waves (2x2), 64x64 per wave,
// 4x4 frags of 16x16x32.  MODE 0: +bias, silu, bf16 out.  MODE 1: +bias, f32 out.
// M hardcoded 4096 (32 row blocks).
template <int MODE>
__global__ __launch_bounds__(256)
void gemm_bf16(const u16* __restrict__ A, const u16* __restrict__ B,
               const float* __restrict__ bias, void* __restrict__ Cout,
               int Kd, int N) {
  __shared__ u16 lsA[128 * 64];   // 16 KB, row stride 128 B, XOR-swizzled 16B chunks
  __shared__ u16 lsB[128 * 64];

  // XCD-bijective swizzle (nwg % 8 == 0 for both GEMMs), colBlk-major for B reuse
  int nwg = (int)gridDim.x;
  int bid = (int)blockIdx.x;
  int cpx = nwg >> 3;
  int L = (bid & 7) * cpx + (bid >> 3);
  int rowBlk = L & 31;
  int colBlk = L >> 5;
  size_t aBase = (size_t)rowBlk * 128 * Kd;
  size_t bBase = (size_t)colBlk * 128 * Kd;

  int tid = threadIdx.x;
  int lane = tid & 63, wid = tid >> 6;
  int wr = wid >> 1, wc = wid & 1;
  int lr = lane & 15, kg = lane >> 4;

  floatx4 acc[4][4] = {};

  for (int k0 = 0; k0 < Kd; k0 += 64) {
    // stage both 128x64 bf16 tiles via global_load_lds width=16.
    // LDS dest is linear; swizzle applied by permuting the GLOBAL source chunk
    // (rule: linear dest + inverse-swizzled source + swizzled read).
    #pragma unroll
    for (int r = 0; r < 4; ++r) {
      uint32_t Lb = (uint32_t)(r * 4096 + wid * 1024);   // wave-uniform LDS byte base
      uint32_t Ll = Lb + (uint32_t)lane * 16u;           // this lane's dest byte
      uint32_t row = Ll >> 7;                            // 128 B per row
      uint32_t c16 = (Ll >> 4) & 7u;                     // 16B chunk within row
      uint32_t cl  = c16 ^ (row & 7u);                   // logical chunk -> source
      const u16* sa = A + aBase + (size_t)row * Kd + (size_t)(k0 + cl * 8);
      const u16* sb = B + bBase + (size_t)row * Kd + (size_t)(k0 + cl * 8);
      __builtin_amdgcn_global_load_lds((const __attribute__((address_space(1))) void*)sa,
                                       (__attribute__((address_space(3))) void*)(lsA + (Lb >> 1)),
                                       16, 0, 0);
      __builtin_amdgcn_global_load_lds((const __attribute__((address_space(1))) void*)sb,
                                       (__attribute__((address_space(3))) void*)(lsB + (Lb >> 1)),
                                       16, 0, 0);
    }
    __syncthreads();

    #pragma unroll
    for (int ks = 0; ks < 2; ++ks) {
      short8 af[4], bfv[4];
      #pragma unroll
      for (int m = 0; m < 4; ++m) {
        uint32_t row = (uint32_t)(wr * 64 + m * 16 + lr);
        uint32_t c16 = ((uint32_t)(ks * 4 + kg)) ^ (row & 7u);
        af[m] = *(const short8*)((const char*)lsA + row * 128u + c16 * 16u);
      }
      #pragma unroll
      for (int n = 0; n < 4; ++n) {
        uint32_t row = (uint32_t)(wc * 64 + n * 16 + lr);
        uint32_t c16 = ((uint32_t)(ks * 4 + kg)) ^ (row & 7u);
        bfv[n] = *(const short8*)((const char*)lsB + row * 128u + c16 * 16u);
      }
      #pragma unroll
      for (int m = 0; m < 4; ++m)
        #pragma unroll
        for (int n = 0; n < 4; ++n)
          acc[m][n] = __builtin_amdgcn_mfma_f32_16x16x32_bf16(af[m], bfv[n], acc[m][n], 0, 0, 0);
    }
    __syncthreads();
  }

  // epilogue: C/D mapping col = lane&15, row = (lane>>4)*4 + reg  [m89-verified]
  int growb = rowBlk * 128 + wr * 64 + kg * 4;
  int gcolb = colBlk * 128 + wc * 64 + lr;
  #pragma unroll
  for (int m = 0; m < 4; ++m) {
    #pragma unroll
    for (int n = 0; n < 4; ++n) {
      int gcol = gcolb + n * 16;
      float bv = bias[gcol];
      #pragma unroll
      for (int r2 = 0; r2 < 4; ++r2) {
        int grow = growb + m * 16 + r2;
        float v = acc[m][n][r2] + bv;
        if (MODE == 0) {
          v = v / (1.0f + __expf(-v));          // silu
          ((u16*)Cout)[(size_t)grow * N + gcol] = f2b(v);
        } else {
          ((float*)Cout)[(size_t)grow * N + gcol] = v;
        }
      }
    }
  }
}

extern "C" void kernel_launch(void* const* d_in, const int* in_sizes, int n_in,
                              void* d_out, int out_size, void* d_ws, size_t ws_size,
                              hipStream_t stream) {
  const int*   tokens = (const int*)d_in[0];      // (T,B) int32
  const float* emb    = (const float*)d_in[1];    // (V,E)
  const float* W1     = (const float*)d_in[2];    // (KE,H)
  const float* b1     = (const float*)d_in[3];    // (H)
  const float* Wout   = (const float*)d_in[4];    // (H,V)
  const float* bout   = (const float*)d_in[5];    // (V)
  float* out = (float*)d_out;                     // (T,B,V) fp32

  // workspace layout (all bf16 as u16):
  u16* X     = (u16*)d_ws;                        // 4096 x 3072   (25.2 MB)
  u16* W1t   = X    + (size_t)M_SZ * KE;          // 2048 x 3072   (12.6 MB)
  u16* Hbuf  = W1t  + (size_t)H_SZ * KE;          // 4096 x 2048   (16.8 MB)
  u16* WoutT = Hbuf + (size_t)M_SZ * H_SZ;        // 32000 x 2048  (131 MB)

  // prep
  build_x<<<(M_SZ * KE / 8) / 256, 256, 0, stream>>>(tokens, emb, X);
  dim3 tb(32, 8);
  transpose_f32_bf16<<<dim3(H_SZ / 32, KE / 32), tb, 0, stream>>>(W1, W1t, KE, H_SZ);
  transpose_f32_bf16<<<dim3(V_SZ / 32, H_SZ / 32), tb, 0, stream>>>(Wout, WoutT, H_SZ, V_SZ);

  // h = silu(X @ W1 + b1) -> bf16      M=4096, N=2048, K=3072
  gemm_bf16<0><<<(M_SZ / 128) * (H_SZ / 128), 256, 0, stream>>>(X, W1t, b1, Hbuf, KE, H_SZ);

  // logits = h @ Wout + bout -> fp32   M=4096, N=32000, K=2048
  gemm_bf16<1><<<(M_SZ / 128) * (V_SZ / 128), 256, 0, stream>>>(Hbuf, WoutT, bout, out, H_SZ, V_SZ);
}